// Round 9
// baseline (118.135 us; speedup 1.0000x reference)
//
#include <hip/hip_runtime.h>
#include <hip/hip_bf16.h>
#include <math.h>

#define B_    2
#define S_    2048
#define DM    512
#define H_    8
#define PROJ  1544
#define NPAD1 1664        // 13*128
#define CHK   64
#define NC    32
#define BS_   4096
#define BH    16

typedef __attribute__((ext_vector_type(8))) short shortx8;
typedef __attribute__((ext_vector_type(4))) short shortx4;
typedef __attribute__((ext_vector_type(4))) float floatx4;

#define GCAST(p) ((const __attribute__((address_space(1))) void*)(p))
#define LCAST(p) ((__attribute__((address_space(3))) void*)(p))

__device__ inline short f2bf(float f) {
    __hip_bfloat16 h = __float2bfloat16(f);
    return *(short*)&h;
}
__device__ inline float bf2f(short s) {
    __hip_bfloat16 h = *(__hip_bfloat16*)&s;
    return __bfloat162float(h);
}
// Read 8 contiguous bf16 (k mult of 8) from a 64-k-wide tile whose 16B groups
// are XOR-swizzled by row: element (row,k) lives at group (k>>3)^(row&7).
__device__ inline shortx8 read8(const short* buf, int row, int k) {
    return *(const shortx8*)&buf[row * 64 + ((((k >> 3) ^ (row & 7))) << 3)];
}

// ---------------------------------------------------------------------------
// fp32->bf16 convert for W1 (zero row-pad to NPAD1) and W2 only.
// x is converted inside gemm1's staging now.
// ---------------------------------------------------------------------------
#define EW1 ((size_t)NPAD1 * DM)
#define EW2 ((size_t)DM * DM)
__global__ __launch_bounds__(256) void convert_w(const float* __restrict__ w1,
                                                 const float* __restrict__ w2,
                                                 short* __restrict__ w1b,
                                                 short* __restrict__ w2b) {
    size_t e = ((size_t)blockIdx.x * 256 + threadIdx.x) * 8;
    const float* src;
    short* dst;
    bool zero = false;
    if (e < EW1) {
        dst = w1b + e;
        size_t row = e >> 9;
        if (row < PROJ) src = w1 + e; else { src = w1; zero = true; }
    } else if (e < EW1 + EW2) {
        size_t o = e - EW1;
        src = w2 + o; dst = w2b + o;
    } else return;
    short out[8];
    if (zero) {
#pragma unroll
        for (int i = 0; i < 8; i++) out[i] = 0;
    } else {
        float4 f0 = *(const float4*)src;
        float4 f1 = *(const float4*)(src + 4);
        out[0] = f2bf(f0.x); out[1] = f2bf(f0.y); out[2] = f2bf(f0.z); out[3] = f2bf(f0.w);
        out[4] = f2bf(f1.x); out[5] = f2bf(f1.y); out[6] = f2bf(f1.z); out[7] = f2bf(f1.w);
    }
    *(shortx8*)dst = *(shortx8*)out;
}

// ---------------------------------------------------------------------------
// gemm2: 64x128-tile, BK=64, XOR-swizzled bf16 MFMA GEMM (256 blocks = 1/CU).
// ---------------------------------------------------------------------------
__global__ __launch_bounds__(256) void gemm_mfma64(const short* __restrict__ A,
                                                   const short* __restrict__ Bw,
                                                   const float* __restrict__ bias,
                                                   float* __restrict__ C,
                                                   int N, int K) {
    __shared__ __align__(16) short As[64 * 64];
    __shared__ __align__(16) short Bs[128 * 64];
    const int tid  = threadIdx.x;
    const int wave = tid >> 6, lane = tid & 63;
    const int m0 = blockIdx.y * 64;
    const int n0 = blockIdx.x * 128;
    const int lrow = lane >> 3;
    const int swz  = ((lane & 7) ^ lrow) << 3;
    const int lm = lane & 15, q = lane >> 4;
    const int wc = wave * 32;
    floatx4 acc[4][2] = {};

    const short* gA0 = A  + (size_t)(m0 +      wave * 8 + lrow) * K + swz;
    const short* gA1 = A  + (size_t)(m0 + 32 + wave * 8 + lrow) * K + swz;
    const short* gB[4];
#pragma unroll
    for (int h = 0; h < 4; h++)
        gB[h] = Bw + (size_t)(n0 + h * 32 + wave * 8 + lrow) * K + swz;

    for (int k0 = 0; k0 < K; k0 += 64) {
        __builtin_amdgcn_global_load_lds(GCAST(gA0 + k0), LCAST(&As[(wave * 8) * 64]),        16, 0, 0);
        __builtin_amdgcn_global_load_lds(GCAST(gA1 + k0), LCAST(&As[(32 + wave * 8) * 64]),   16, 0, 0);
#pragma unroll
        for (int h = 0; h < 4; h++)
            __builtin_amdgcn_global_load_lds(GCAST(gB[h] + k0), LCAST(&Bs[(h * 32 + wave * 8) * 64]), 16, 0, 0);
        __syncthreads();
        shortx8 af[2][4], bw[2][2];
#pragma unroll
        for (int ks = 0; ks < 2; ks++) {
#pragma unroll
            for (int i = 0; i < 4; i++) af[ks][i] = read8(As, i * 16 + lm, ks * 32 + q * 8);
#pragma unroll
            for (int j = 0; j < 2; j++) bw[ks][j] = read8(Bs, wc + j * 16 + lm, ks * 32 + q * 8);
        }
#pragma unroll
        for (int ks = 0; ks < 2; ks++)
#pragma unroll
            for (int i = 0; i < 4; i++)
#pragma unroll
                for (int j = 0; j < 2; j++)
                    acc[i][j] = __builtin_amdgcn_mfma_f32_16x16x32_bf16(af[ks][i], bw[ks][j], acc[i][j], 0, 0, 0);
        __syncthreads();
    }
#pragma unroll
    for (int i = 0; i < 4; i++) {
        int rb = m0 + i * 16 + q * 4;
#pragma unroll
        for (int j = 0; j < 2; j++) {
            int col = n0 + wc + j * 16 + lm;
            float bv = bias[col];
#pragma unroll
            for (int r = 0; r < 4; r++)
                C[(size_t)(rb + r) * N + col] = acc[i][j][r] + bv;
        }
    }
}

// ---------------------------------------------------------------------------
// gemm1 (64x128, BK=64, swizzled): A is fp32 x, converted to bf16 in-register
// during staging (ds_write_b128, swizzled layout); B staged via
// global_load_lds. Fused epilogue -> q, k, kT, vT (bf16) + gate (fp32).
// ---------------------------------------------------------------------------
__global__ __launch_bounds__(256) void gemm1_fused(const float* __restrict__ X,
                                                   const short* __restrict__ Bw,
                                                   const float* __restrict__ bias,
                                                   short* __restrict__ qb,
                                                   short* __restrict__ kb,
                                                   short* __restrict__ kTb,
                                                   short* __restrict__ vTb,
                                                   float* __restrict__ gateb) {
    __shared__ __align__(16) short As[64 * 64];
    __shared__ __align__(16) short Bs[128 * 64];
    const int K = DM;
    const int tid  = threadIdx.x;
    const int wave = tid >> 6, lane = tid & 63;
    const int m0 = blockIdx.y * 64;
    const int n0 = blockIdx.x * 128;
    const int lrow = lane >> 3;
    const int swz  = ((lane & 7) ^ lrow) << 3;
    const int lm = lane & 15, q = lane >> 4;
    const int wc = wave * 32;
    floatx4 acc[4][2] = {};

    // A staging assignment: thread owns row arow (0..63), k-groups ag, ag+1.
    const int arow = tid >> 2;
    const int ag   = (tid & 3) * 2;
    const float* gX = X + (size_t)(m0 + arow) * K + ag * 8;
    short* wp0 = &As[arow * 64 + (((ag    ) ^ (arow & 7)) << 3)];
    short* wp1 = &As[arow * 64 + (((ag + 1) ^ (arow & 7)) << 3)];

    const short* gB[4];
#pragma unroll
    for (int h = 0; h < 4; h++)
        gB[h] = Bw + (size_t)(n0 + h * 32 + wave * 8 + lrow) * K + swz;

    for (int k0 = 0; k0 < K; k0 += 64) {
#pragma unroll
        for (int h = 0; h < 4; h++)
            __builtin_amdgcn_global_load_lds(GCAST(gB[h] + k0), LCAST(&Bs[(h * 32 + wave * 8) * 64]), 16, 0, 0);
        {
            float4 f0 = *(const float4*)(gX + k0);
            float4 f1 = *(const float4*)(gX + k0 + 4);
            float4 f2 = *(const float4*)(gX + k0 + 8);
            float4 f3 = *(const float4*)(gX + k0 + 12);
            short t0[8] = { f2bf(f0.x), f2bf(f0.y), f2bf(f0.z), f2bf(f0.w),
                            f2bf(f1.x), f2bf(f1.y), f2bf(f1.z), f2bf(f1.w) };
            short t1[8] = { f2bf(f2.x), f2bf(f2.y), f2bf(f2.z), f2bf(f2.w),
                            f2bf(f3.x), f2bf(f3.y), f2bf(f3.z), f2bf(f3.w) };
            *(shortx8*)wp0 = *(shortx8*)t0;
            *(shortx8*)wp1 = *(shortx8*)t1;
        }
        __syncthreads();
        shortx8 af[2][4], bw[2][2];
#pragma unroll
        for (int ks = 0; ks < 2; ks++) {
#pragma unroll
            for (int i = 0; i < 4; i++) af[ks][i] = read8(As, i * 16 + lm, ks * 32 + q * 8);
#pragma unroll
            for (int j = 0; j < 2; j++) bw[ks][j] = read8(Bs, wc + j * 16 + lm, ks * 32 + q * 8);
        }
#pragma unroll
        for (int ks = 0; ks < 2; ks++)
#pragma unroll
            for (int i = 0; i < 4; i++)
#pragma unroll
                for (int j = 0; j < 2; j++)
                    acc[i][j] = __builtin_amdgcn_mfma_f32_16x16x32_bf16(af[ks][i], bw[ks][j], acc[i][j], 0, 0, 0);
        __syncthreads();
    }

    const int bIdx = m0 >> 11;
    const int bh0  = bIdx * H_;
#pragma unroll
    for (int i = 0; i < 4; i++) {
        int s0 = (m0 & (S_ - 1)) + i * 16 + q * 4;
#pragma unroll
        for (int j = 0; j < 2; j++) {
            int col = n0 + wc + j * 16 + lm;
            float bv = (col < PROJ) ? bias[col] : 0.f;
            float vals[4];
#pragma unroll
            for (int r = 0; r < 4; r++) vals[r] = acc[i][j][r] + bv;
            if (col < 512) {                       // v -> vT[bh][v][s]
                int h = col >> 6, vd = col & 63;
                short tmp[4];
#pragma unroll
                for (int r = 0; r < 4; r++) tmp[r] = f2bf(vals[r]);
                *(shortx4*)&vTb[((size_t)(bh0 + h) * 64 + vd) * S_ + s0] = *(shortx4*)tmp;
            } else if (col < 1024) {               // q -> q[bh][s][d]
                int h = (col >> 6) - 8, d = col & 63;
                size_t rb = ((size_t)(bh0 + h) * S_ + s0) * 64 + d;
#pragma unroll
                for (int r = 0; r < 4; r++) qb[rb + (size_t)r * 64] = f2bf(vals[r]);
            } else if (col < 1536) {               // k -> k[bh][t][d] and kT[bh][d][t]
                int h = (col >> 6) - 16, d = col & 63;
                size_t rb = ((size_t)(bh0 + h) * S_ + s0) * 64 + d;
                short tmp[4];
#pragma unroll
                for (int r = 0; r < 4; r++) { tmp[r] = f2bf(vals[r]); kb[rb + (size_t)r * 64] = tmp[r]; }
                *(shortx4*)&kTb[((size_t)(bh0 + h) * 64 + d) * S_ + s0] = *(shortx4*)tmp;
            } else if (col < PROJ) {               // n -> gate[bh][s]
                int h = col - 1536;
                float g[4];
#pragma unroll
                for (int r = 0; r < 4; r++) g[r] = __expf(-__expf(vals[r]));
                *(float4*)&gateb[(size_t)(bh0 + h) * S_ + s0] = make_float4(g[0], g[1], g[2], g[3]);
            }
        }
    }
}

// ---------------------------------------------------------------------------
// Per-chunk state via MFMA: U[v][d] = sum_{s in chunk} V[s][v] * K[s][d]
// ---------------------------------------------------------------------------
__global__ __launch_bounds__(256) void chunk_kv_mfma(const short* __restrict__ vTb,
                                                     const short* __restrict__ kTb,
                                                     float* __restrict__ kvbuf) {
    __shared__ __align__(16) short VT[64 * 64];
    __shared__ __align__(16) short KT[64 * 64];
    const int blk = blockIdx.x;
    const int c = blk & (NC - 1), bh = blk >> 5;
    const int base = c * CHK;
    const int tid = threadIdx.x, wave = tid >> 6, lane = tid & 63;
    const int lrow = lane >> 3, lgrp = lane & 7;

#pragma unroll
    for (int half = 0; half < 2; half++) {
        int v0 = wave * 8 + half * 32;
        int row = v0 + lrow;
        int gcol = ((lgrp ^ (row & 7)) << 3);
        __builtin_amdgcn_global_load_lds(GCAST(vTb + ((size_t)(bh * 64 + row)) * S_ + base + gcol),
                                         LCAST(&VT[v0 * 64]), 16, 0, 0);
        __builtin_amdgcn_global_load_lds(GCAST(kTb + ((size_t)(bh * 64 + row)) * S_ + base + gcol),
                                         LCAST(&KT[v0 * 64]), 16, 0, 0);
    }
    __syncthreads();

    const int lm = lane & 15, q = lane >> 4;
    const int wr = (wave >> 1) * 32, wc = (wave & 1) * 32;
    floatx4 acc[2][2] = {};
#pragma unroll
    for (int ks = 0; ks < 2; ks++) {
        shortx8 a[2], b2[2];
#pragma unroll
        for (int i = 0; i < 2; i++) a[i]  = read8(VT, wr + i * 16 + lm, ks * 32 + q * 8);
#pragma unroll
        for (int j = 0; j < 2; j++) b2[j] = read8(KT, wc + j * 16 + lm, ks * 32 + q * 8);
#pragma unroll
        for (int i = 0; i < 2; i++)
#pragma unroll
            for (int j = 0; j < 2; j++)
                acc[i][j] = __builtin_amdgcn_mfma_f32_16x16x32_bf16(a[i], b2[j], acc[i][j], 0, 0, 0);
    }
    float* outp = kvbuf + ((size_t)blk << 12);
#pragma unroll
    for (int i = 0; i < 2; i++)
#pragma unroll
        for (int j = 0; j < 2; j++)
#pragma unroll
            for (int r = 0; r < 4; r++)
                outp[(wr + i * 16 + q * 4 + r) * 64 + wc + j * 16 + lm] = acc[i][j][r];
}

// ---------------------------------------------------------------------------
// Group-of-4 exclusive prefix over chunk states:
// kvg[bh][g][e] = sum_{c < 4g} U[c][e],  g = 0..7.
// ---------------------------------------------------------------------------
__global__ __launch_bounds__(256) void scan_groups(const float* __restrict__ kvbuf,
                                                   float* __restrict__ kvg) {
    const int blk = blockIdx.x;
    const int bh = blk >> 4, seg = blk & 15;
    const int e = seg * 256 + threadIdx.x;
    const float* src = kvbuf + (((size_t)bh * NC) << 12) + e;
    float* dst = kvg + (((size_t)bh * 8) << 12) + e;
    float run = 0.f;
#pragma unroll
    for (int g = 0; g < 8; g++) {
        dst[(size_t)g << 12] = run;
#pragma unroll
        for (int cc = 0; cc < 4; cc++)
            run += src[(size_t)(g * 4 + cc) << 12];
    }
}

// ---------------------------------------------------------------------------
// MFMA attention chunk. Prefix = kvg[c>>2] + <=3 chunk states (fp32).
// LDS exactly 40 KB (S aliases the Ks buffer, swizzled) -> 4 blocks/CU.
// ---------------------------------------------------------------------------
__global__ __launch_bounds__(256) void attn_mfma(const short* __restrict__ qb,
                                                 const short* __restrict__ kb,
                                                 const short* __restrict__ vTb,
                                                 const float* __restrict__ gateb,
                                                 const float* __restrict__ kvbuf,
                                                 const float* __restrict__ kvg,
                                                 short* __restrict__ ctxb) {
    __shared__ __align__(16) short Qs[64 * 64];
    __shared__ __align__(16) short KsSb[64 * 64];   // Ks in phase 1, S after
    __shared__ __align__(16) short VTs[64 * 64];
    __shared__ __align__(16) short Phi[64 * 64];
    __shared__ __align__(16) short Plo[64 * 64];
    const int blk = blockIdx.x;
    const int bh = blk & (BH - 1);
    const int c  = (NC - 1) - (blk >> 4);
    const int base = c * CHK;
    const int tid = threadIdx.x, wave = tid >> 6, lane = tid & 63;
    const int lrow = lane >> 3, lgrp = lane & 7;

#pragma unroll
    for (int half = 0; half < 2; half++) {
        int v0 = wave * 8 + half * 32;
        int row = v0 + lrow;
        int gcol = ((lgrp ^ (row & 7)) << 3);
        __builtin_amdgcn_global_load_lds(GCAST(qb + ((size_t)bh * S_ + base + row) * 64 + gcol),
                                         LCAST(&Qs[v0 * 64]), 16, 0, 0);
        __builtin_amdgcn_global_load_lds(GCAST(kb + ((size_t)bh * S_ + base + row) * 64 + gcol),
                                         LCAST(&KsSb[v0 * 64]), 16, 0, 0);
        __builtin_amdgcn_global_load_lds(GCAST(vTb + ((size_t)(bh * 64 + row)) * S_ + base + gcol),
                                         LCAST(&VTs[v0 * 64]), 16, 0, 0);
    }

    // Prefix = group prefix + <=3 preceding chunks within the group (fp32).
    float pacc[16];
    {
        const float* gp = kvg + (((size_t)bh * 8 + (c >> 2)) << 12) + tid;
#pragma unroll
        for (int it = 0; it < 16; it++) pacc[it] = gp[it * 256];
        const float* kvb = kvbuf + (((size_t)bh * NC) << 12) + tid;
        for (int cp = c & ~3; cp < c; cp++) {
            const float* p = kvb + ((size_t)cp << 12);
#pragma unroll
            for (int it = 0; it < 16; it++) pacc[it] += p[it * 256];
        }
    }
#pragma unroll
    for (int it = 0; it < 16; it++) {
        int idx = it * 256 + tid;
        int v = idx >> 6, d = idx & 63;
        float f = pacc[it];
        short hi = f2bf(f);
        short lo = f2bf(f - bf2f(hi));
        int sw = v * 64 + (((d >> 3) ^ (v & 7)) << 3) + (d & 7);
        Phi[sw] = hi; Plo[sw] = lo;
    }
    __syncthreads();

    const int lm = lane & 15, q = lane >> 4;
    const int wr = (wave >> 1) * 32, wc = (wave & 1) * 32;

    // Phase 1: S quadrant = Q K^T (reads KsSb as Ks)
    floatx4 sacc[2][2] = {};
#pragma unroll
    for (int ks = 0; ks < 2; ks++) {
        shortx8 qa[2], kf[2];
#pragma unroll
        for (int i = 0; i < 2; i++) qa[i] = read8(Qs, wr + i * 16 + lm, ks * 32 + q * 8);
#pragma unroll
        for (int j = 0; j < 2; j++) kf[j] = read8(KsSb, wc + j * 16 + lm, ks * 32 + q * 8);
#pragma unroll
        for (int i = 0; i < 2; i++)
#pragma unroll
            for (int j = 0; j < 2; j++)
                sacc[i][j] = __builtin_amdgcn_mfma_f32_16x16x32_bf16(qa[i], kf[j], sacc[i][j], 0, 0, 0);
    }
    __syncthreads();   // all Ks reads done before S overwrites the buffer

    // causal mask -> S into KsSb (swizzled layout, same as read8 expects)
#pragma unroll
    for (int i = 0; i < 2; i++)
#pragma unroll
        for (int j = 0; j < 2; j++)
#pragma unroll
            for (int r = 0; r < 4; r++) {
                int s = wr + i * 16 + q * 4 + r;
                int t = wc + j * 16 + lm;
                KsSb[s * 64 + (((t >> 3) ^ (s & 7)) << 3) + (t & 7)] =
                    f2bf(t <= s ? sacc[i][j][r] : 0.f);
            }
    __syncthreads();

    // Phase 2: O = S.V + Q.(Phi+Plo)
    floatx4 oacc[2][2] = {};
#pragma unroll
    for (int ks = 0; ks < 2; ks++) {
        shortx8 sa[2], vb[2];
#pragma unroll
        for (int i = 0; i < 2; i++) sa[i] = read8(KsSb, wr + i * 16 + lm, ks * 32 + q * 8);
#pragma unroll
        for (int j = 0; j < 2; j++) vb[j] = read8(VTs, wc + j * 16 + lm, ks * 32 + q * 8);
#pragma unroll
        for (int i = 0; i < 2; i++)
#pragma unroll
            for (int j = 0; j < 2; j++)
                oacc[i][j] = __builtin_amdgcn_mfma_f32_16x16x32_bf16(sa[i], vb[j], oacc[i][j], 0, 0, 0);
    }
#pragma unroll
    for (int ks = 0; ks < 2; ks++) {
        shortx8 qa[2], ph[2], pl[2];
#pragma unroll
        for (int i = 0; i < 2; i++) qa[i] = read8(Qs, wr + i * 16 + lm, ks * 32 + q * 8);
#pragma unroll
        for (int j = 0; j < 2; j++) {
            ph[j] = read8(Phi, wc + j * 16 + lm, ks * 32 + q * 8);
            pl[j] = read8(Plo, wc + j * 16 + lm, ks * 32 + q * 8);
        }
#pragma unroll
        for (int i = 0; i < 2; i++)
#pragma unroll
            for (int j = 0; j < 2; j++) {
                oacc[i][j] = __builtin_amdgcn_mfma_f32_16x16x32_bf16(qa[i], ph[j], oacc[i][j], 0, 0, 0);
                oacc[i][j] = __builtin_amdgcn_mfma_f32_16x16x32_bf16(qa[i], pl[j], oacc[i][j], 0, 0, 0);
            }
    }
    const size_t tok0 = (size_t)(bh >> 3) * S_ + base;
    const int h = bh & 7;
    const float* gaterow = gateb + (size_t)bh * S_ + base;
#pragma unroll
    for (int i = 0; i < 2; i++)
#pragma unroll
        for (int j = 0; j < 2; j++)
#pragma unroll
            for (int r = 0; r < 4; r++) {
                int s = wr + i * 16 + q * 4 + r;
                int v = wc + j * 16 + lm;
                ctxb[(tok0 + s) * DM + h * 64 + v] = f2bf(gaterow[s] * oacc[i][j][r]);
            }
}

// ---------------------------------------------------------------------------
extern "C" void kernel_launch(void* const* d_in, const int* in_sizes, int n_in,
                              void* d_out, int out_size, void* d_ws, size_t ws_size,
                              hipStream_t stream) {
    const float* x       = (const float*)d_in[0];
    const float* Wvqkn_w = (const float*)d_in[1];
    const float* Wvqkn_b = (const float*)d_in[2];
    const float* out_w   = (const float*)d_in[3];
    const float* out_b   = (const float*)d_in[4];
    float* out = (float*)d_out;

    float* kvbuf = (float*)d_ws;                          // 16*32*4096 f32
    float* kvg   = kvbuf + (size_t)BH * NC * 4096;        // 16*8*4096 f32
    short* w1b   = (short*)(kvg + (size_t)BH * 8 * 4096);
    short* w2b   = w1b  + (size_t)NPAD1 * DM;
    short* ctxb  = w2b  + (size_t)DM * DM;
    short* qb    = ctxb + (size_t)BS_ * DM;
    short* kb    = qb   + (size_t)BH * S_ * 64;
    short* kTb   = kb   + (size_t)BH * S_ * 64;
    short* vTb   = kTb  + (size_t)BH * S_ * 64;
    float* gateb = (float*)(vTb + (size_t)BH * S_ * 64);

    convert_w<<<(int)((EW1 + EW2) / 8 / 256), 256, 0, stream>>>(Wvqkn_w, out_w, w1b, w2b);

    gemm1_fused<<<dim3(NPAD1 / 128, BS_ / 64), 256, 0, stream>>>(
        x, w1b, Wvqkn_b, qb, kb, kTb, vTb, gateb);

    chunk_kv_mfma<<<BH * NC, 256, 0, stream>>>(vTb, kTb, kvbuf);
    scan_groups<<<BH * 16, 256, 0, stream>>>(kvbuf, kvg);
    attn_mfma<<<BH * NC, 256, 0, stream>>>(qb, kb, vTb, gateb, kvbuf, kvg, ctxb);

    gemm_mfma64<<<dim3(DM / 128, BS_ / 64), 256, 0, stream>>>(ctxb, w2b, out_b, out, DM, DM);
}

// Round 10
// 110.403 us; speedup vs baseline: 1.0700x; 1.0700x over previous
//
#include <hip/hip_runtime.h>
#include <hip/hip_bf16.h>
#include <math.h>

#define B_    2
#define S_    2048
#define DM    512
#define H_    8
#define PROJ  1544
#define NPAD1 1664        // 13*128
#define CHK   64
#define NC    32
#define BS_   4096
#define BH    16

typedef __attribute__((ext_vector_type(8))) short shortx8;
typedef __attribute__((ext_vector_type(4))) short shortx4;
typedef __attribute__((ext_vector_type(4))) float floatx4;

#define GCAST(p) ((const __attribute__((address_space(1))) void*)(p))
#define LCAST(p) ((__attribute__((address_space(3))) void*)(p))

__device__ inline short f2bf(float f) {
    __hip_bfloat16 h = __float2bfloat16(f);
    return *(short*)&h;
}
__device__ inline float bf2f(short s) {
    __hip_bfloat16 h = *(__hip_bfloat16*)&s;
    return __bfloat162float(h);
}
// Read 8 contiguous bf16 (k mult of 8) from a 64-k-wide tile whose 16B groups
// are XOR-swizzled by row: element (row,k) lives at group (k>>3)^(row&7).
__device__ inline shortx8 read8(const short* buf, int row, int k) {
    return *(const shortx8*)&buf[row * 64 + ((((k >> 3) ^ (row & 7))) << 3)];
}

// ---------------------------------------------------------------------------
// One fused fp32->bf16 convert for x, W1 (zero row-pad to NPAD1), W2.
// ---------------------------------------------------------------------------
#define E1 ((size_t)BS_ * DM)
#define E2 ((size_t)NPAD1 * DM)
#define E3 ((size_t)DM * DM)
__global__ __launch_bounds__(256) void convert_all(const float* __restrict__ x,
                                                   const float* __restrict__ w1,
                                                   const float* __restrict__ w2,
                                                   short* __restrict__ xb,
                                                   short* __restrict__ w1b,
                                                   short* __restrict__ w2b) {
    size_t e = ((size_t)blockIdx.x * 256 + threadIdx.x) * 8;
    const float* src;
    short* dst;
    bool zero = false;
    if (e < E1) { src = x + e; dst = xb + e; }
    else if (e < E1 + E2) {
        size_t o = e - E1;
        dst = w1b + o;
        size_t row = o >> 9;
        if (row < PROJ) src = w1 + o; else { src = w1; zero = true; }
    } else if (e < E1 + E2 + E3) {
        size_t o = e - E1 - E2;
        src = w2 + o; dst = w2b + o;
    } else return;
    short out[8];
    if (zero) {
#pragma unroll
        for (int i = 0; i < 8; i++) out[i] = 0;
    } else {
        float4 f0 = *(const float4*)src;
        float4 f1 = *(const float4*)(src + 4);
        out[0] = f2bf(f0.x); out[1] = f2bf(f0.y); out[2] = f2bf(f0.z); out[3] = f2bf(f0.w);
        out[4] = f2bf(f1.x); out[5] = f2bf(f1.y); out[6] = f2bf(f1.z); out[7] = f2bf(f1.w);
    }
    *(shortx8*)dst = *(shortx8*)out;
}

// ---------------------------------------------------------------------------
// gemm2: 64x128-tile, BK=64, XOR-swizzled bf16 MFMA GEMM (256 blocks = 1/CU).
// ---------------------------------------------------------------------------
__global__ __launch_bounds__(256) void gemm_mfma64(const short* __restrict__ A,
                                                   const short* __restrict__ Bw,
                                                   const float* __restrict__ bias,
                                                   float* __restrict__ C,
                                                   int N, int K) {
    __shared__ __align__(16) short As[64 * 64];
    __shared__ __align__(16) short Bs[128 * 64];
    const int tid  = threadIdx.x;
    const int wave = tid >> 6, lane = tid & 63;
    const int m0 = blockIdx.y * 64;
    const int n0 = blockIdx.x * 128;
    const int lrow = lane >> 3;
    const int swz  = ((lane & 7) ^ lrow) << 3;
    const int lm = lane & 15, q = lane >> 4;
    const int wc = wave * 32;
    floatx4 acc[4][2] = {};

    const short* gA0 = A  + (size_t)(m0 +      wave * 8 + lrow) * K + swz;
    const short* gA1 = A  + (size_t)(m0 + 32 + wave * 8 + lrow) * K + swz;
    const short* gB[4];
#pragma unroll
    for (int h = 0; h < 4; h++)
        gB[h] = Bw + (size_t)(n0 + h * 32 + wave * 8 + lrow) * K + swz;

    for (int k0 = 0; k0 < K; k0 += 64) {
        __builtin_amdgcn_global_load_lds(GCAST(gA0 + k0), LCAST(&As[(wave * 8) * 64]),        16, 0, 0);
        __builtin_amdgcn_global_load_lds(GCAST(gA1 + k0), LCAST(&As[(32 + wave * 8) * 64]),   16, 0, 0);
#pragma unroll
        for (int h = 0; h < 4; h++)
            __builtin_amdgcn_global_load_lds(GCAST(gB[h] + k0), LCAST(&Bs[(h * 32 + wave * 8) * 64]), 16, 0, 0);
        __syncthreads();
        shortx8 af[2][4], bw[2][2];
#pragma unroll
        for (int ks = 0; ks < 2; ks++) {
#pragma unroll
            for (int i = 0; i < 4; i++) af[ks][i] = read8(As, i * 16 + lm, ks * 32 + q * 8);
#pragma unroll
            for (int j = 0; j < 2; j++) bw[ks][j] = read8(Bs, wc + j * 16 + lm, ks * 32 + q * 8);
        }
#pragma unroll
        for (int ks = 0; ks < 2; ks++)
#pragma unroll
            for (int i = 0; i < 4; i++)
#pragma unroll
                for (int j = 0; j < 2; j++)
                    acc[i][j] = __builtin_amdgcn_mfma_f32_16x16x32_bf16(af[ks][i], bw[ks][j], acc[i][j], 0, 0, 0);
        __syncthreads();
    }
#pragma unroll
    for (int i = 0; i < 4; i++) {
        int rb = m0 + i * 16 + q * 4;
#pragma unroll
        for (int j = 0; j < 2; j++) {
            int col = n0 + wc + j * 16 + lm;
            float bv = bias[col];
#pragma unroll
            for (int r = 0; r < 4; r++)
                C[(size_t)(rb + r) * N + col] = acc[i][j][r] + bv;
        }
    }
}

// ---------------------------------------------------------------------------
// gemm1 (64x128, BK=64, swizzled) with fused epilogue producing q[bh][s][d],
// k[bh][t][d], kT[bh][d][s], vT[bh][v][s] (bf16), gate[bh][s] fp32.
// ---------------------------------------------------------------------------
__global__ __launch_bounds__(256) void gemm1_fused(const short* __restrict__ A,
                                                   const short* __restrict__ Bw,
                                                   const float* __restrict__ bias,
                                                   short* __restrict__ qb,
                                                   short* __restrict__ kb,
                                                   short* __restrict__ kTb,
                                                   short* __restrict__ vTb,
                                                   float* __restrict__ gateb) {
    __shared__ __align__(16) short As[64 * 64];
    __shared__ __align__(16) short Bs[128 * 64];
    const int K = DM;
    const int tid  = threadIdx.x;
    const int wave = tid >> 6, lane = tid & 63;
    const int m0 = blockIdx.y * 64;
    const int n0 = blockIdx.x * 128;
    const int lrow = lane >> 3;
    const int swz  = ((lane & 7) ^ lrow) << 3;
    const int lm = lane & 15, q = lane >> 4;
    const int wc = wave * 32;
    floatx4 acc[4][2] = {};

    const short* gA0 = A  + (size_t)(m0 +      wave * 8 + lrow) * K + swz;
    const short* gA1 = A  + (size_t)(m0 + 32 + wave * 8 + lrow) * K + swz;
    const short* gB[4];
#pragma unroll
    for (int h = 0; h < 4; h++)
        gB[h] = Bw + (size_t)(n0 + h * 32 + wave * 8 + lrow) * K + swz;

    for (int k0 = 0; k0 < K; k0 += 64) {
        __builtin_amdgcn_global_load_lds(GCAST(gA0 + k0), LCAST(&As[(wave * 8) * 64]),        16, 0, 0);
        __builtin_amdgcn_global_load_lds(GCAST(gA1 + k0), LCAST(&As[(32 + wave * 8) * 64]),   16, 0, 0);
#pragma unroll
        for (int h = 0; h < 4; h++)
            __builtin_amdgcn_global_load_lds(GCAST(gB[h] + k0), LCAST(&Bs[(h * 32 + wave * 8) * 64]), 16, 0, 0);
        __syncthreads();
        shortx8 af[2][4], bw[2][2];
#pragma unroll
        for (int ks = 0; ks < 2; ks++) {
#pragma unroll
            for (int i = 0; i < 4; i++) af[ks][i] = read8(As, i * 16 + lm, ks * 32 + q * 8);
#pragma unroll
            for (int j = 0; j < 2; j++) bw[ks][j] = read8(Bs, wc + j * 16 + lm, ks * 32 + q * 8);
        }
#pragma unroll
        for (int ks = 0; ks < 2; ks++)
#pragma unroll
            for (int i = 0; i < 4; i++)
#pragma unroll
                for (int j = 0; j < 2; j++)
                    acc[i][j] = __builtin_amdgcn_mfma_f32_16x16x32_bf16(af[ks][i], bw[ks][j], acc[i][j], 0, 0, 0);
        __syncthreads();
    }

    const int bIdx = m0 >> 11;
    const int bh0  = bIdx * H_;
#pragma unroll
    for (int i = 0; i < 4; i++) {
        int s0 = (m0 & (S_ - 1)) + i * 16 + q * 4;
#pragma unroll
        for (int j = 0; j < 2; j++) {
            int col = n0 + wc + j * 16 + lm;
            float bv = (col < PROJ) ? bias[col] : 0.f;
            float vals[4];
#pragma unroll
            for (int r = 0; r < 4; r++) vals[r] = acc[i][j][r] + bv;
            if (col < 512) {                       // v -> vT[bh][v][s]
                int h = col >> 6, vd = col & 63;
                short tmp[4];
#pragma unroll
                for (int r = 0; r < 4; r++) tmp[r] = f2bf(vals[r]);
                *(shortx4*)&vTb[((size_t)(bh0 + h) * 64 + vd) * S_ + s0] = *(shortx4*)tmp;
            } else if (col < 1024) {               // q -> q[bh][s][d]
                int h = (col >> 6) - 8, d = col & 63;
                size_t rb = ((size_t)(bh0 + h) * S_ + s0) * 64 + d;
#pragma unroll
                for (int r = 0; r < 4; r++) qb[rb + (size_t)r * 64] = f2bf(vals[r]);
            } else if (col < 1536) {               // k -> k[bh][t][d] and kT[bh][d][t]
                int h = (col >> 6) - 16, d = col & 63;
                size_t rb = ((size_t)(bh0 + h) * S_ + s0) * 64 + d;
                short tmp[4];
#pragma unroll
                for (int r = 0; r < 4; r++) { tmp[r] = f2bf(vals[r]); kb[rb + (size_t)r * 64] = tmp[r]; }
                *(shortx4*)&kTb[((size_t)(bh0 + h) * 64 + d) * S_ + s0] = *(shortx4*)tmp;
            } else if (col < PROJ) {               // n -> gate[bh][s]
                int h = col - 1536;
                float g[4];
#pragma unroll
                for (int r = 0; r < 4; r++) g[r] = __expf(-__expf(vals[r]));
                *(float4*)&gateb[(size_t)(bh0 + h) * S_ + s0] = make_float4(g[0], g[1], g[2], g[3]);
            }
        }
    }
}

// ---------------------------------------------------------------------------
// Grouped chunk states (replaces chunk_kv + scan_groups):
// 128 blocks = (bh, g). Each block processes chunks 4g..4g+3 sequentially,
// accumulating in the SAME MFMA accumulators, writing the in-group INCLUSIVE
// prefix after each chunk: kvbuf[bh][c] = sum_{c' in group, c'<=c} U_{c'}.
// Group sum == kvbuf[bh][4g+3]. Zero extra arithmetic vs separate scan.
// ---------------------------------------------------------------------------
__global__ __launch_bounds__(256) void chunk_kv_grouped(const short* __restrict__ vTb,
                                                        const short* __restrict__ kTb,
                                                        float* __restrict__ kvbuf) {
    __shared__ __align__(16) short VT[64 * 64];
    __shared__ __align__(16) short KT[64 * 64];
    const int blk = blockIdx.x;            // 0..127
    const int bh = blk >> 3, g = blk & 7;
    const int tid = threadIdx.x, wave = tid >> 6, lane = tid & 63;
    const int lrow = lane >> 3, lgrp = lane & 7;
    const int lm = lane & 15, q = lane >> 4;
    const int wr = (wave >> 1) * 32, wc = (wave & 1) * 32;
    floatx4 acc[2][2] = {};

    for (int cc = 0; cc < 4; cc++) {
        const int c = g * 4 + cc;
        const int base = c * CHK;
#pragma unroll
        for (int half = 0; half < 2; half++) {
            int v0 = wave * 8 + half * 32;
            int row = v0 + lrow;
            int gcol = ((lgrp ^ (row & 7)) << 3);
            __builtin_amdgcn_global_load_lds(GCAST(vTb + ((size_t)(bh * 64 + row)) * S_ + base + gcol),
                                             LCAST(&VT[v0 * 64]), 16, 0, 0);
            __builtin_amdgcn_global_load_lds(GCAST(kTb + ((size_t)(bh * 64 + row)) * S_ + base + gcol),
                                             LCAST(&KT[v0 * 64]), 16, 0, 0);
        }
        __syncthreads();
#pragma unroll
        for (int ks = 0; ks < 2; ks++) {
            shortx8 a[2], b2[2];
#pragma unroll
            for (int i = 0; i < 2; i++) a[i]  = read8(VT, wr + i * 16 + lm, ks * 32 + q * 8);
#pragma unroll
            for (int j = 0; j < 2; j++) b2[j] = read8(KT, wc + j * 16 + lm, ks * 32 + q * 8);
#pragma unroll
            for (int i = 0; i < 2; i++)
#pragma unroll
                for (int j = 0; j < 2; j++)
                    acc[i][j] = __builtin_amdgcn_mfma_f32_16x16x32_bf16(a[i], b2[j], acc[i][j], 0, 0, 0);
        }
        float* outp = kvbuf + (((size_t)bh * NC + c) << 12);
#pragma unroll
        for (int i = 0; i < 2; i++)
#pragma unroll
            for (int j = 0; j < 2; j++)
#pragma unroll
                for (int r = 0; r < 4; r++)
                    outp[(wr + i * 16 + q * 4 + r) * 64 + wc + j * 16 + lm] = acc[i][j][r];
        __syncthreads();   // LDS reads done in all waves before next staging
    }
}

// ---------------------------------------------------------------------------
// MFMA attention chunk. Prefix = sum_{g'<g} kvbuf[4g'+3]  (group sums)
//                              + (c&3 ? kvbuf[c-1] : 0)   (in-group prefix).
// LDS exactly 40 KB (S aliases the Ks buffer, swizzled) -> 4 blocks/CU.
// ---------------------------------------------------------------------------
__global__ __launch_bounds__(256) void attn_mfma(const short* __restrict__ qb,
                                                 const short* __restrict__ kb,
                                                 const short* __restrict__ vTb,
                                                 const float* __restrict__ gateb,
                                                 const float* __restrict__ kvbuf,
                                                 short* __restrict__ ctxb) {
    __shared__ __align__(16) short Qs[64 * 64];
    __shared__ __align__(16) short KsSb[64 * 64];   // Ks in phase 1, S after
    __shared__ __align__(16) short VTs[64 * 64];
    __shared__ __align__(16) short Phi[64 * 64];
    __shared__ __align__(16) short Plo[64 * 64];
    const int blk = blockIdx.x;
    const int bh = blk & (BH - 1);
    const int c  = (NC - 1) - (blk >> 4);   // heavy chunks dispatched first
    const int base = c * CHK;
    const int tid = threadIdx.x, wave = tid >> 6, lane = tid & 63;
    const int lrow = lane >> 3, lgrp = lane & 7;

#pragma unroll
    for (int half = 0; half < 2; half++) {
        int v0 = wave * 8 + half * 32;
        int row = v0 + lrow;
        int gcol = ((lgrp ^ (row & 7)) << 3);
        __builtin_amdgcn_global_load_lds(GCAST(qb + ((size_t)bh * S_ + base + row) * 64 + gcol),
                                         LCAST(&Qs[v0 * 64]), 16, 0, 0);
        __builtin_amdgcn_global_load_lds(GCAST(kb + ((size_t)bh * S_ + base + row) * 64 + gcol),
                                         LCAST(&KsSb[v0 * 64]), 16, 0, 0);
        __builtin_amdgcn_global_load_lds(GCAST(vTb + ((size_t)(bh * 64 + row)) * S_ + base + gcol),
                                         LCAST(&VTs[v0 * 64]), 16, 0, 0);
    }

    // Prefix from grouped inclusive states.
    float pacc[16] = {};
    {
        const float* kvb = kvbuf + (((size_t)bh * NC) << 12) + tid;
        const int g = c >> 2;
        for (int gp = 0; gp < g; gp++) {
            const float* p = kvb + ((size_t)(gp * 4 + 3) << 12);
#pragma unroll
            for (int it = 0; it < 16; it++) pacc[it] += p[it * 256];
        }
        if (c & 3) {
            const float* p = kvb + ((size_t)(c - 1) << 12);
#pragma unroll
            for (int it = 0; it < 16; it++) pacc[it] += p[it * 256];
        }
    }
#pragma unroll
    for (int it = 0; it < 16; it++) {
        int idx = it * 256 + tid;
        int v = idx >> 6, d = idx & 63;
        float f = pacc[it];
        short hi = f2bf(f);
        short lo = f2bf(f - bf2f(hi));
        int sw = v * 64 + (((d >> 3) ^ (v & 7)) << 3) + (d & 7);
        Phi[sw] = hi; Plo[sw] = lo;
    }
    __syncthreads();

    const int lm = lane & 15, q = lane >> 4;
    const int wr = (wave >> 1) * 32, wc = (wave & 1) * 32;

    // Phase 1: S quadrant = Q K^T (reads KsSb as Ks)
    floatx4 sacc[2][2] = {};
#pragma unroll
    for (int ks = 0; ks < 2; ks++) {
        shortx8 qa[2], kf[2];
#pragma unroll
        for (int i = 0; i < 2; i++) qa[i] = read8(Qs, wr + i * 16 + lm, ks * 32 + q * 8);
#pragma unroll
        for (int j = 0; j < 2; j++) kf[j] = read8(KsSb, wc + j * 16 + lm, ks * 32 + q * 8);
#pragma unroll
        for (int i = 0; i < 2; i++)
#pragma unroll
            for (int j = 0; j < 2; j++)
                sacc[i][j] = __builtin_amdgcn_mfma_f32_16x16x32_bf16(qa[i], kf[j], sacc[i][j], 0, 0, 0);
    }
    __syncthreads();   // all Ks reads done before S overwrites the buffer

    // causal mask -> S into KsSb (swizzled layout, same as read8 expects)
#pragma unroll
    for (int i = 0; i < 2; i++)
#pragma unroll
        for (int j = 0; j < 2; j++)
#pragma unroll
            for (int r = 0; r < 4; r++) {
                int s = wr + i * 16 + q * 4 + r;
                int t = wc + j * 16 + lm;
                KsSb[s * 64 + (((t >> 3) ^ (s & 7)) << 3) + (t & 7)] =
                    f2bf(t <= s ? sacc[i][j][r] : 0.f);
            }
    __syncthreads();

    // Phase 2: O = S.V + Q.(Phi+Plo)
    floatx4 oacc[2][2] = {};
#pragma unroll
    for (int ks = 0; ks < 2; ks++) {
        shortx8 sa[2], vb[2];
#pragma unroll
        for (int i = 0; i < 2; i++) sa[i] = read8(KsSb, wr + i * 16 + lm, ks * 32 + q * 8);
#pragma unroll
        for (int j = 0; j < 2; j++) vb[j] = read8(VTs, wc + j * 16 + lm, ks * 32 + q * 8);
#pragma unroll
        for (int i = 0; i < 2; i++)
#pragma unroll
            for (int j = 0; j < 2; j++)
                oacc[i][j] = __builtin_amdgcn_mfma_f32_16x16x32_bf16(sa[i], vb[j], oacc[i][j], 0, 0, 0);
    }
#pragma unroll
    for (int ks = 0; ks < 2; ks++) {
        shortx8 qa[2], ph[2], pl[2];
#pragma unroll
        for (int i = 0; i < 2; i++) qa[i] = read8(Qs, wr + i * 16 + lm, ks * 32 + q * 8);
#pragma unroll
        for (int j = 0; j < 2; j++) {
            ph[j] = read8(Phi, wc + j * 16 + lm, ks * 32 + q * 8);
            pl[j] = read8(Plo, wc + j * 16 + lm, ks * 32 + q * 8);
        }
#pragma unroll
        for (int i = 0; i < 2; i++)
#pragma unroll
            for (int j = 0; j < 2; j++) {
                oacc[i][j] = __builtin_amdgcn_mfma_f32_16x16x32_bf16(qa[i], ph[j], oacc[i][j], 0, 0, 0);
                oacc[i][j] = __builtin_amdgcn_mfma_f32_16x16x32_bf16(qa[i], pl[j], oacc[i][j], 0, 0, 0);
            }
    }
    const size_t tok0 = (size_t)(bh >> 3) * S_ + base;
    const int h = bh & 7;
    const float* gaterow = gateb + (size_t)bh * S_ + base;
#pragma unroll
    for (int i = 0; i < 2; i++)
#pragma unroll
        for (int j = 0; j < 2; j++)
#pragma unroll
            for (int r = 0; r < 4; r++) {
                int s = wr + i * 16 + q * 4 + r;
                int v = wc + j * 16 + lm;
                ctxb[(tok0 + s) * DM + h * 64 + v] = f2bf(gaterow[s] * oacc[i][j][r]);
            }
}

// ---------------------------------------------------------------------------
extern "C" void kernel_launch(void* const* d_in, const int* in_sizes, int n_in,
                              void* d_out, int out_size, void* d_ws, size_t ws_size,
                              hipStream_t stream) {
    const float* x       = (const float*)d_in[0];
    const float* Wvqkn_w = (const float*)d_in[1];
    const float* Wvqkn_b = (const float*)d_in[2];
    const float* out_w   = (const float*)d_in[3];
    const float* out_b   = (const float*)d_in[4];
    float* out = (float*)d_out;

    float* kvbuf = (float*)d_ws;                          // 16*32*4096 f32
    short* xb    = (short*)(kvbuf + (size_t)BH * NC * 4096);
    short* w1b   = xb   + (size_t)BS_ * DM;
    short* w2b   = w1b  + (size_t)NPAD1 * DM;
    short* ctxb  = w2b  + (size_t)DM * DM;
    short* qb    = ctxb + (size_t)BS_ * DM;
    short* kb    = qb   + (size_t)BH * S_ * 64;
    short* kTb   = kb   + (size_t)BH * S_ * 64;
    short* vTb   = kTb  + (size_t)BH * S_ * 64;
    float* gateb = (float*)(vTb + (size_t)BH * S_ * 64);

    convert_all<<<(int)((E1 + E2 + E3) / 8 / 256), 256, 0, stream>>>(
        x, Wvqkn_w, out_w, xb, w1b, w2b);

    gemm1_fused<<<dim3(NPAD1 / 128, BS_ / 64), 256, 0, stream>>>(
        xb, w1b, Wvqkn_b, qb, kb, kTb, vTb, gateb);

    chunk_kv_grouped<<<BH * 8, 256, 0, stream>>>(vTb, kTb, kvbuf);
    attn_mfma<<<BH * NC, 256, 0, stream>>>(qb, kb, vTb, gateb, kvbuf, ctxb);

    gemm_mfma64<<<dim3(DM / 128, BS_ / 64), 256, 0, stream>>>(ctxb, w2b, out_b, out, DM, DM);
}